// Round 19
// baseline (81.792 us; speedup 1.0000x reference)
//
#include <hip/hip_runtime.h>
#include <math.h>

#define NFEAT 256
#define NROWS 65536
#define PCOUNT 4194304
#define PBLK 64                      // param-reduce blocks appended to pass1 grid
#define CH2 512                      // pass2 fallback chunks
#define RGRP 16                      // reduce_S c-groups
#define NSLOT 28                     // P1 slots per chunk per feature
#define F_EPS 5.9604645e-07f         // float32 eps * 5
#define F_LN2 0.69314718056f
#define DELTA_MAX 0.45f              // poly-validity gate on |0.1*rp|

#define FAST_LOG2(v) __builtin_log2f(v)   // v_log_f32
#define FAST_EXP2(v) __builtin_exp2f(v)   // v_exp_f32

constexpr double D_HALF_LOG2_2PIE = 0.5 * 2.8378770664093453 / 0.6931471805599453;
constexpr double D_LAMBDA_BITS = 13.287712379549449; // 2*log2(100)

__device__ inline double wave_reduce_add(double v) {
  for (int o = 32; o > 0; o >>= 1) v += __shfl_down(v, o, 64);
  return v;
}

// sum_k d^k/k! * m[k], k=0..5 (Horner)
__device__ inline double horner_exp(const double* m, double d) {
  double p = m[5] * (1.0 / 120.0);
  p = p * d + m[4] * (1.0 / 24.0);
  p = p * d + m[3] * (1.0 / 6.0);
  p = p * d + m[2] * 0.5;
  p = p * d + m[1];
  p = p * d + m[0];
  return p;
}

// ---------------------------------------------------------------------------
// Pass 1 (split-moment form): 512-thread blocks, thread = (f=tid&255,
// half=tid>>8). Both halves scan the SAME rows; half 0 accumulates Taylor
// moment orders k=0..2 of {Mp,Mp2,Mn,Mn2} (+u2p,u2a,npos), half 1 orders
// k=3..5. Cost: u/q/B recomputed per half (+1 log +1 exp per elem total);
// benefit: 12-15 accumulators/thread = ~32-40 VGPR = r10's footprint that
// sustained 85% VALUBusy (r16/r17's 27-accumulator kernel pinned VGPR=36
// and collapsed to 35-40% busy on serial load-use scheduling).
// Moments: M_k = sum B*q^k, M2_k = sum B^2*q^k; B = exp2(center*u),
// q = u*ln2, u = log2(1+|x|). Reconstruction per-feature in f64 in k_pick
// (5th-order Taylor, same truncation as r13 -> absmax 0.0).
// Slot ownership (disjoint per half, both modes):
//  half0: {0,1,2, 6,7,8, 12,13,14, 18,19,20, 24,25,26,27}
//  half1: {3,4,5, 9,10,11, 15,16,17, 21,22,23}
// Moment mode: slots 0..5 Mp(k), 6..11 Mp2, 12..17 Mn, 18..23 Mn2,
// 24 u2p, 25 u2a, 26 npos, 27 flag=0.
// Direct mode (flag=1, lambda special cases): 0..5 sum_y_j, 6..11 sum_y2_j
// (half h owns j = 3h..3h+2), moment slots zeroed.
// Blocks >= CHv: parameter tensor reduction (overlapped, memory-bound).
// ---------------------------------------------------------------------------
__global__ __launch_bounds__(512, 4) void k_pass1(
    const float* __restrict__ x, const float* __restrict__ lam1,
    const float* __restrict__ lam2, const float* __restrict__ rp,
    const float* __restrict__ params, float* __restrict__ P1,
    double* __restrict__ pSums, int CHv, int rpt)
{
  const int c = blockIdx.x;
  const int tid = threadIdx.x;

  if (c >= CHv) {
    // ---- parameter tensor partial reduction ----
    __shared__ double lred[2][8];
    const int b = c - CHv;
    const float4* p4 = (const float4*)params;
    double s = 0.0, q = 0.0;
    for (int i = b * 512 + tid; i < PCOUNT / 4; i += PBLK * 512) {
      float4 v = p4[i];
      s += (double)v.x + (double)v.y + (double)v.z + (double)v.w;
      q += (double)v.x * v.x + (double)v.y * v.y
         + (double)v.z * v.z + (double)v.w * v.w;
    }
    s = wave_reduce_add(s); q = wave_reduce_add(q);
    const int w = tid >> 6;
    if ((tid & 63) == 0) { lred[0][w] = s; lred[1][w] = q; }
    __syncthreads();
    if (tid == 0) {
      double S = 0.0, Q = 0.0;
#pragma unroll
      for (int i = 0; i < 8; ++i) { S += lred[0][i]; Q += lred[1][i]; }
      atomicAdd(&pSums[0], S);
      atomicAdd(&pSums[1], Q);
    }
    return;
  }

  const int f = tid & 255;
  const int half = tid >> 8;           // 0: orders 0..2 / j=0..2; 1: orders 3..5 / j=3..5
  __shared__ int bad;
  if (tid == 0) bad = 0;
  __syncthreads();

  const float L1 = lam1[f], L2 = lam2[f];
  const float An = 2.0f - L2;          // negative-branch center
  {
    bool b = (fabsf(L1) < F_EPS) || (fabsf(An) < F_EPS);
#pragma unroll
    for (int j = 1; j < 6; ++j) {
      float dp = 0.1f * rp[f * 10 + 2 * (j - 1)];
      float dn = -0.1f * rp[f * 10 + 2 * (j - 1) + 1];
      b = b || (fabsf(L1 + dp) < F_EPS) || (fabsf(An + dn) < F_EPS)
            || (fabsf(dp) > DELTA_MAX) || (fabsf(dn) > DELTA_MAX);
    }
    if (b) bad = 1;  // benign same-value race
  }
  __syncthreads();

  const float* xp = x + (size_t)c * rpt * NFEAT + f;

  if (bad == 0) {
    // ---- moment path: 12 accumulators + (half0: 3 scalars) ----
    float M[12];                       // [g*3+m], g=0:Mp 1:Mp2 2:Mn 3:Mn2
#pragma unroll
    for (int k = 0; k < 12; ++k) M[k] = 0.f;
    float u2p = 0.f, u2a = 0.f, npos = 0.f;

#pragma unroll 4
    for (int i = 0; i < rpt; ++i) {
      const float v = xp[(size_t)i * NFEAT];
      const bool pos = v >= 0.0f;
      const float u = FAST_LOG2(1.0f + fabsf(v));
      if (half == 0) {                 // wave-uniform branch
        u2a += u;
        u2p += pos ? u : 0.0f;
        npos += pos ? 1.0f : 0.0f;
      }
      const float q = u * F_LN2;
      const float B = FAST_EXP2((pos ? L1 : An) * u);
      const float B2 = B * B;
      const float Bp = pos ? B : 0.0f;
      const float Bn = B - Bp;
      const float Cp = pos ? B2 : 0.0f;
      const float Cn = B2 - Cp;
      float w0;
      if (half == 0) w0 = 1.0f;
      else { const float q2 = q * q; w0 = q2 * q; }
      const float w1 = w0 * q;
      const float w2 = w1 * q;
      M[0] = fmaf(Bp, w0, M[0]); M[1] = fmaf(Bp, w1, M[1]); M[2]  = fmaf(Bp, w2, M[2]);
      M[3] = fmaf(Cp, w0, M[3]); M[4] = fmaf(Cp, w1, M[4]); M[5]  = fmaf(Cp, w2, M[5]);
      M[6] = fmaf(Bn, w0, M[6]); M[7] = fmaf(Bn, w1, M[7]); M[8]  = fmaf(Bn, w2, M[8]);
      M[9] = fmaf(Cn, w0, M[9]); M[10]= fmaf(Cn, w1, M[10]); M[11]= fmaf(Cn, w2, M[11]);
    }
#pragma unroll
    for (int g = 0; g < 4; ++g) {
      const int base = g * 6 + half * 3;
#pragma unroll
      for (int m = 0; m < 3; ++m)
        P1[((size_t)c * NSLOT + base + m) * NFEAT + f] = M[g * 3 + m];
    }
    if (half == 0) {
      P1[((size_t)c * NSLOT + 24) * NFEAT + f] = u2p;
      P1[((size_t)c * NSLOT + 25) * NFEAT + f] = u2a;
      P1[((size_t)c * NSLOT + 26) * NFEAT + f] = npos;
      P1[((size_t)c * NSLOT + 27) * NFEAT + f] = 0.0f;
    }
  } else {
    // ---- exact general path: 3 proposals per half, direct sums ----
    float ga_p[3], ga_n[3], gs_p[3], gs_n[3], gt_p[3], gt_n[3];
#pragma unroll
    for (int m = 0; m < 3; ++m) {
      const int j = half * 3 + m;
      float dp = (j == 0) ? 0.0f : 0.1f * rp[f * 10 + 2 * (j - 1)];
      float dn = (j == 0) ? 0.0f : -0.1f * rp[f * 10 + 2 * (j - 1) + 1];
      float a1 = L1 + dp;
      float a2 = An + dn;
      bool z1 = fabsf(a1) < F_EPS;
      bool z2 = fabsf(a2) < F_EPS;
      ga_p[m] = z1 ? 0.0f : a1;
      gs_p[m] = z1 ? 0.0f : 1.0f / a1;
      gt_p[m] = z1 ? F_LN2 : 0.0f;
      ga_n[m] = z2 ? 0.0f : a2;
      gs_n[m] = z2 ? 0.0f : -1.0f / a2;
      gt_n[m] = z2 ? -F_LN2 : 0.0f;
    }
    float as[3], aq[3];
#pragma unroll
    for (int m = 0; m < 3; ++m) { as[m] = 0.f; aq[m] = 0.f; }
    float u2p = 0.f, u2a = 0.f;
    for (int i = 0; i < rpt; ++i) {
      float v = xp[(size_t)i * NFEAT];
      bool pos = v >= 0.0f;
      float u2 = FAST_LOG2(1.0f + fabsf(v));
      u2a += u2;
      u2p += pos ? u2 : 0.0f;
#pragma unroll
      for (int m = 0; m < 3; ++m) {
        float a  = pos ? ga_p[m] : ga_n[m];
        float s  = pos ? gs_p[m] : gs_n[m];
        float tt = pos ? gt_p[m] : gt_n[m];
        float e = FAST_EXP2(a * u2);
        float y = fmaf(tt, u2, fmaf(s, e, -s));
        as[m] += y;
        aq[m] = fmaf(y, y, aq[m]);
      }
    }
#pragma unroll
    for (int m = 0; m < 3; ++m) {
      const int j = half * 3 + m;
      P1[((size_t)c * NSLOT + j) * NFEAT + f]      = as[m];
      P1[((size_t)c * NSLOT + 6 + j) * NFEAT + f]  = aq[m];
      P1[((size_t)c * NSLOT + 12 + j) * NFEAT + f] = 0.0f;
      P1[((size_t)c * NSLOT + 18 + j) * NFEAT + f] = 0.0f;
    }
    if (half == 0) {
      P1[((size_t)c * NSLOT + 24) * NFEAT + f] = u2p;
      P1[((size_t)c * NSLOT + 25) * NFEAT + f] = u2a;
      P1[((size_t)c * NSLOT + 26) * NFEAT + f] = 0.0f;
      P1[((size_t)c * NSLOT + 27) * NFEAT + f] = 1.0f;
    }
  }
}

// Stage A reduce: block (k, cg): S2[(k*RGRP+cg)*NFEAT+f] = sum over c-subrange.
__global__ __launch_bounds__(256) void k_reduce_S(
    const float* __restrict__ P1, double* __restrict__ S2, int CHv)
{
  const int k = blockIdx.x / RGRP;
  const int cg = blockIdx.x % RGRP;
  const int f = threadIdx.x;
  const int per = CHv / RGRP;
  const int c0 = cg * per;
  double a0 = 0.0, a1 = 0.0, a2 = 0.0, a3 = 0.0;
  for (int c = c0; c < c0 + per; c += 4) {
    a0 += (double)P1[((size_t)(c + 0) * NSLOT + k) * NFEAT + f];
    a1 += (double)P1[((size_t)(c + 1) * NSLOT + k) * NFEAT + f];
    a2 += (double)P1[((size_t)(c + 2) * NSLOT + k) * NFEAT + f];
    a3 += (double)P1[((size_t)(c + 3) * NSLOT + k) * NFEAT + f];
  }
  S2[((size_t)k * RGRP + cg) * NFEAT + f] = (a0 + a1) + (a2 + a3);
}

// One thread per feature: reconstruct 6 scores in f64, min, tie-average.
__global__ __launch_bounds__(256) void k_pick(
    const double* __restrict__ S2, const float* __restrict__ lam1,
    const float* __restrict__ lam2, const float* __restrict__ rp,
    float* __restrict__ bestL, int* __restrict__ tied,
    double* __restrict__ bitsF, int* __restrict__ anyTied)
{
  const int f = threadIdx.x;
  if (f == 0) *anyTied = 0;
  double s[NSLOT];
#pragma unroll
  for (int k = 0; k < NSLOT; ++k) {
    double a = 0.0;
#pragma unroll
    for (int cg = 0; cg < RGRP; ++cg)
      a += S2[((size_t)k * RGRP + cg) * NFEAT + f];
    s[k] = a;
  }
  const double n = (double)NROWS;
  const bool direct = s[27] > 0.5;
  const double npos = s[26];
  const double nneg = n - npos;
  const double sup = s[24];
  const double sun = s[25] - s[24];
  const float L1 = lam1[f], L2 = lam2[f];
  const double dAn = 2.0 - (double)L2;   // f64 negative-branch center
  double scores[6], al1[6], al2[6];
#pragma unroll
  for (int j = 0; j < 6; ++j) {
    float l1 = (j == 0) ? L1 : L1 + 0.1f * rp[f * 10 + 2 * (j - 1)];
    float l2 = (j == 0) ? L2 : L2 + 0.1f * rp[f * 10 + 2 * (j - 1) + 1];
    al1[j] = (double)l1; al2[j] = (double)l2;
    bool z1 = fabsf(l1) < F_EPS;
    bool z2 = fabsf(l2 - 2.0f) < F_EPS;
    double ccp = z1 ? -1.0 : (double)l1 - 1.0;
    double ccn = z2 ? -1.0 : 1.0 - (double)l2;
    double ljb = ccp * sup + ccn * sun;

    double sum_y, sum_y2;
    if (direct) {
      sum_y  = s[j];
      sum_y2 = s[6 + j];
    } else {
      const double dp  = (double)l1 - (double)L1;
      const double dnn = (2.0 - (double)l2) - dAn;
      const double sp = 1.0 / ((double)L1 + dp);
      const double sn = -1.0 / (dAn + dnn);
      const double Ep  = horner_exp(&s[0],  dp);
      const double Ep2 = horner_exp(&s[6],  2.0 * dp);
      const double En  = horner_exp(&s[12], dnn);
      const double En2 = horner_exp(&s[18], 2.0 * dnn);
      sum_y  = sp * (Ep - npos) + sn * (En - nneg);
      sum_y2 = sp * sp * (Ep2 - 2.0 * Ep + npos)
             + sn * sn * (En2 - 2.0 * En + nneg);
    }
    double mean = sum_y / n;
    double var = sum_y2 / n - mean * mean;
    var = var > 1e-12 ? var : 1e-12;
    scores[j] = n * (D_HALF_LOG2_2PIE + 0.5 * log2(var)) + ljb + D_LAMBDA_BITS;
  }
  double mn = scores[0];
#pragma unroll
  for (int j = 1; j < 6; ++j) mn = scores[j] < mn ? scores[j] : mn;
  double wsum = 0.0, b1 = 0.0, b2 = 0.0;
#pragma unroll
  for (int j = 0; j < 6; ++j) {
    double w = (scores[j] == mn) ? 1.0 : 0.0;
    wsum += w; b1 += w * al1[j]; b2 += w * al2[j];
  }
  bestL[2 * f]     = (float)(b1 / wsum);
  bestL[2 * f + 1] = (float)(b2 / wsum);
  const int isTied = (wsum > 1.5) ? 1 : 0;
  tied[f] = isTied;
  if (isTied) atomicOr(anyTied, 1);
  bitsF[f] = mn;   // unique min: identical to re-evaluating at best lambda
}

// Fallback pass 2 (only if some feature tied: averaged lambda is new).
__global__ __launch_bounds__(256) void k_pass2(
    const float* __restrict__ x, const float* __restrict__ bestL,
    const int* __restrict__ anyTied, float* __restrict__ P2)
{
  if (*anyTied == 0) return;
  const int t = threadIdx.x;
  const int c = blockIdx.x;
  const int rpt = NROWS / CH2;   // 128
  const float l1 = bestL[2 * t], l2 = bestL[2 * t + 1];
  const bool z1 = fabsf(l1) < F_EPS;
  const bool z2 = fabsf(l2 - 2.0f) < F_EPS;
  const float tm = 2.0f - l2;
  const float a_p = z1 ? 0.f : l1,  s_pv = z1 ? 0.f : 1.f / l1,  t_pv = z1 ? F_LN2 : 0.f;
  const float a_n = z2 ? 0.f : tm,  s_nv = z2 ? 0.f : -1.f / tm, t_nv = z2 ? -F_LN2 : 0.f;

  float sy = 0.f, sq = 0.f;
  const float* xp = x + (size_t)c * rpt * NFEAT + t;
  for (int i = 0; i < rpt; ++i) {
    float v = xp[(size_t)i * NFEAT];
    bool pos = v >= 0.0f;
    float u2 = FAST_LOG2(1.0f + fabsf(v));
    float a  = pos ? a_p : a_n;
    float s  = pos ? s_pv : s_nv;
    float tt = pos ? t_pv : t_nv;
    float e = FAST_EXP2(a * u2);
    float y = fmaf(tt, u2, fmaf(s, e, -s));
    sy += y;
    sq = fmaf(y, y, sq);
  }
  P2[((size_t)c * 2 + 0) * NFEAT + t] = sy;
  P2[((size_t)c * 2 + 1) * NFEAT + t] = sq;
}

__global__ __launch_bounds__(64) void k_featbits(
    const float* __restrict__ P1, const float* __restrict__ P2,
    const float* __restrict__ bestL, const int* __restrict__ tied,
    double* __restrict__ bitsF, int CHv)
{
  const int f = blockIdx.x;
  if (!tied[f]) return;
  const int lane = threadIdx.x;
  double s0 = 0.0, s1 = 0.0, sup = 0.0, sua = 0.0;
  for (int c = lane; c < CH2; c += 64) {
    s0 += (double)P2[((size_t)c * 2 + 0) * NFEAT + f];
    s1 += (double)P2[((size_t)c * 2 + 1) * NFEAT + f];
  }
  for (int c = lane; c < CHv; c += 64) {
    sup += (double)P1[((size_t)c * NSLOT + 24) * NFEAT + f];
    sua += (double)P1[((size_t)c * NSLOT + 25) * NFEAT + f];
  }
  s0 = wave_reduce_add(s0); s1 = wave_reduce_add(s1);
  sup = wave_reduce_add(sup); sua = wave_reduce_add(sua);
  if (lane == 0) {
    const float l1 = bestL[2 * f], l2 = bestL[2 * f + 1];
    bool z1 = fabsf(l1) < F_EPS;
    bool z2 = fabsf(l2 - 2.0f) < F_EPS;
    double ccp = z1 ? -1.0 : (double)l1 - 1.0;
    double ccn = z2 ? -1.0 : 1.0 - (double)l2;
    double ljb = ccp * sup + ccn * (sua - sup);
    const double n = (double)NROWS;
    double mean = s0 / n;
    double var = s1 / n - mean * mean;
    var = var > 1e-12 ? var : 1e-12;
    bitsF[f] = n * (D_HALF_LOG2_2PIE + 0.5 * log2(var)) + ljb + D_LAMBDA_BITS;
  }
}

__global__ __launch_bounds__(256) void k_final(
    const double* __restrict__ bitsF, const double* __restrict__ pSums,
    float* __restrict__ out)
{
  __shared__ double l[4];
  double s = bitsF[threadIdx.x];
  s = wave_reduce_add(s);
  int w = threadIdx.x >> 6;
  if ((threadIdx.x & 63) == 0) l[w] = s;
  __syncthreads();
  if (threadIdx.x == 0) {
    double data = l[0] + l[1] + l[2] + l[3];
    const double n = (double)PCOUNT;
    double mean = pSums[0] / n;
    double var = pSums[1] / n - mean * mean;
    var = var > 1e-12 ? var : 1e-12;
    double model = n * (D_HALF_LOG2_2PIE + 0.5 * log2(var)) + D_LAMBDA_BITS;
    out[0] = (float)(data + model);
  }
}

extern "C" void kernel_launch(void* const* d_in, const int* in_sizes, int n_in,
                              void* d_out, int out_size, void* d_ws, size_t ws_size,
                              hipStream_t stream)
{
  const float* x      = (const float*)d_in[0];
  const float* lam1   = (const float*)d_in[1];
  const float* lam2   = (const float*)d_in[2];
  const float* rp     = (const float*)d_in[3];
  const float* params = (const float*)d_in[4];

  char* ws = (char*)d_ws;
  double* pSums  = (double*)ws;                 // 16 B   -> 16
  float*  bestL  = (float*)(ws + 16);           // 2048   -> 2064
  double* bitsF  = (double*)(ws + 2064);        // 2048   -> 4112
  int*    tied   = (int*)(ws + 4112);           // 1024   -> 5136
  int*    anyT   = (int*)(ws + 5136);           // 4      -> pad 5152
  double* S2     = (double*)(ws + 5152);        // 28*16*256*8 = 917504 -> 922656
  float*  P1     = (float*)(ws + 922656);

  // chunk count: CHv=1024 (r16's best P1 traffic), fall back if ws small
  int CHv = 1024;
  while (CHv > 128) {
    size_t need = 922656 + (size_t)CHv * NSLOT * NFEAT * 4
                         + (size_t)CH2 * 2 * NFEAT * 4;
    if (need <= ws_size) break;
    CHv >>= 1;
  }
  float* P2 = (float*)(ws + 922656 + (size_t)CHv * NSLOT * NFEAT * 4);
  int rpt = NROWS / CHv;   // 64 at CHv=1024

  (void)hipMemsetAsync(pSums, 0, 16, stream);
  k_pass1<<<CHv + PBLK, 512, 0, stream>>>(x, lam1, lam2, rp, params, P1,
                                          pSums, CHv, rpt);
  k_reduce_S<<<NSLOT * RGRP, 256, 0, stream>>>(P1, S2, CHv);
  k_pick<<<1, 256, 0, stream>>>(S2, lam1, lam2, rp, bestL, tied, bitsF, anyT);
  k_pass2<<<CH2, 256, 0, stream>>>(x, bestL, anyT, P2);
  k_featbits<<<NFEAT, 64, 0, stream>>>(P1, P2, bestL, tied, bitsF, CHv);
  k_final<<<1, 256, 0, stream>>>(bitsF, pSums, (float*)d_out);
}

// Round 22
// 80.259 us; speedup vs baseline: 1.0191x; 1.0191x over previous
//
#include <hip/hip_runtime.h>
#include <math.h>

#define NFEAT 256
#define NROWS 65536
#define PCOUNT 4194304
#define PBLK 64                      // param-reduce blocks appended to pass1 grid
#define CH2 512                      // pass2 fallback chunks
#define RGRP 16                      // reduce_S c-groups
#define NSLOT 28                     // P1 slots per chunk per feature
#define F_EPS 5.9604645e-07f         // float32 eps * 5
#define F_LN2 0.69314718056f
#define DELTA_MAX 0.45f              // poly-validity gate on |0.1*rp|

#define FAST_LOG2(v) __builtin_log2f(v)   // v_log_f32
#define FAST_EXP2(v) __builtin_exp2f(v)   // v_exp_f32

typedef float v2f __attribute__((ext_vector_type(2)));

constexpr double D_HALF_LOG2_2PIE = 0.5 * 2.8378770664093453 / 0.6931471805599453;
constexpr double D_LAMBDA_BITS = 13.287712379549449; // 2*log2(100)

__device__ inline double wave_reduce_add(double v) {
  for (int o = 32; o > 0; o >>= 1) v += __shfl_down(v, o, 64);
  return v;
}

// sum_k d^k/k! * m[k], k=0..5 (Horner)
__device__ inline double horner_exp(const double* m, double d) {
  double p = m[5] * (1.0 / 120.0);
  p = p * d + m[4] * (1.0 / 24.0);
  p = p * d + m[3] * (1.0 / 6.0);
  p = p * d + m[2] * 0.5;
  p = p * d + m[1];
  p = p * d + m[0];
  return p;
}

// ---------------------------------------------------------------------------
// Pass 1 (split-moment, packed-FP32): 512-thread blocks, thread = (f=tid&255,
// half=tid>>8). Both halves scan the SAME rows; half h owns Taylor orders
// k=3h..3h+2. Moment fmas packed as float2 (pos,neg) lanes ->
// v_pk_fma_f32 via __builtin_elementwise_fma: 6 pk-fma/half vs 12 scalar
// (r19: VALUBusy 72% but busy-time 36.7us of redundant support ops).
// Moments: M_k = sum B*q^k, M2_k = sum B^2*q^k; B = exp2(center*u),
// q = u*ln2, u = log2(1+|x|). Reconstruction per-feature in f64 in k_pick
// (5th-order Taylor, same truncation as r13 -> absmax 0.0).
// Slots: 0..5 Mp(k), 6..11 Mp2, 12..17 Mn, 18..23 Mn2, 24 u2p, 25 u2a,
// 26 npos, 27 flag (1 = direct sums from exact general path; half h owns
// j=3h..3h+2 there).
// Blocks >= CHv: parameter tensor reduction (overlapped, memory-bound).
// ---------------------------------------------------------------------------
__global__ __launch_bounds__(512, 4) void k_pass1(
    const float* __restrict__ x, const float* __restrict__ lam1,
    const float* __restrict__ lam2, const float* __restrict__ rp,
    const float* __restrict__ params, float* __restrict__ P1,
    double* __restrict__ pSums, int CHv, int rpt)
{
  const int c = blockIdx.x;
  const int tid = threadIdx.x;

  if (c >= CHv) {
    // ---- parameter tensor partial reduction ----
    __shared__ double lred[2][8];
    const int b = c - CHv;
    const float4* p4 = (const float4*)params;
    double s = 0.0, q = 0.0;
    for (int i = b * 512 + tid; i < PCOUNT / 4; i += PBLK * 512) {
      float4 v = p4[i];
      s += (double)v.x + (double)v.y + (double)v.z + (double)v.w;
      q += (double)v.x * v.x + (double)v.y * v.y
         + (double)v.z * v.z + (double)v.w * v.w;
    }
    s = wave_reduce_add(s); q = wave_reduce_add(q);
    const int w = tid >> 6;
    if ((tid & 63) == 0) { lred[0][w] = s; lred[1][w] = q; }
    __syncthreads();
    if (tid == 0) {
      double S = 0.0, Q = 0.0;
#pragma unroll
      for (int i = 0; i < 8; ++i) { S += lred[0][i]; Q += lred[1][i]; }
      atomicAdd(&pSums[0], S);
      atomicAdd(&pSums[1], Q);
    }
    return;
  }

  const int f = tid & 255;
  const int half = tid >> 8;           // wave-uniform
  __shared__ int bad;
  if (tid == 0) bad = 0;
  __syncthreads();

  const float L1 = lam1[f], L2 = lam2[f];
  const float An = 2.0f - L2;          // negative-branch center
  {
    bool b = (fabsf(L1) < F_EPS) || (fabsf(An) < F_EPS);
#pragma unroll
    for (int j = 1; j < 6; ++j) {
      float dp = 0.1f * rp[f * 10 + 2 * (j - 1)];
      float dn = -0.1f * rp[f * 10 + 2 * (j - 1) + 1];
      b = b || (fabsf(L1 + dp) < F_EPS) || (fabsf(An + dn) < F_EPS)
            || (fabsf(dp) > DELTA_MAX) || (fabsf(dn) > DELTA_MAX);
    }
    if (b) bad = 1;  // benign same-value race
  }
  __syncthreads();

  const float* xp = x + (size_t)c * rpt * NFEAT + f;

  if (bad == 0) {
    // ---- moment path: 6 float2 accumulators (12 regs) + half0 scalars ----
    v2f MB[3], MC[3];                  // MB[m]=(Mp_k, Mn_k), MC[m]=(Mp2_k, Mn2_k)
#pragma unroll
    for (int m = 0; m < 3; ++m) { MB[m] = (v2f)(0.f); MC[m] = (v2f)(0.f); }
    float u2p = 0.f, u2a = 0.f, npos = 0.f;

#pragma unroll 4
    for (int i = 0; i < rpt; ++i) {
      const float v = xp[(size_t)i * NFEAT];
      const bool pos = v >= 0.0f;
      const float u = FAST_LOG2(1.0f + fabsf(v));
      if (half == 0) {                 // wave-uniform branch
        u2a += u;
        u2p += pos ? u : 0.0f;
        npos += pos ? 1.0f : 0.0f;
      }
      const float q = u * F_LN2;
      const float B = FAST_EXP2((pos ? L1 : An) * u);
      const float B2 = B * B;
      const v2f BV = pos ? (v2f){B, 0.f}  : (v2f){0.f, B};
      const v2f CV = pos ? (v2f){B2, 0.f} : (v2f){0.f, B2};
      float w0;
      if (half == 0) w0 = 1.0f;
      else { const float q2 = q * q; w0 = q2 * q; }
      const float w1 = w0 * q;
      const float w2 = w1 * q;
      const v2f W0 = (v2f){w0, w0};
      const v2f W1 = (v2f){w1, w1};
      const v2f W2 = (v2f){w2, w2};
      MB[0] = __builtin_elementwise_fma(BV, W0, MB[0]);
      MB[1] = __builtin_elementwise_fma(BV, W1, MB[1]);
      MB[2] = __builtin_elementwise_fma(BV, W2, MB[2]);
      MC[0] = __builtin_elementwise_fma(CV, W0, MC[0]);
      MC[1] = __builtin_elementwise_fma(CV, W1, MC[1]);
      MC[2] = __builtin_elementwise_fma(CV, W2, MC[2]);
    }
    // store: Mp -> 0..5, Mp2 -> 6..11, Mn -> 12..17, Mn2 -> 18..23
#pragma unroll
    for (int m = 0; m < 3; ++m) {
      const int k = half * 3 + m;
      P1[((size_t)c * NSLOT + k) * NFEAT + f]      = MB[m].x;
      P1[((size_t)c * NSLOT + 6 + k) * NFEAT + f]  = MC[m].x;
      P1[((size_t)c * NSLOT + 12 + k) * NFEAT + f] = MB[m].y;
      P1[((size_t)c * NSLOT + 18 + k) * NFEAT + f] = MC[m].y;
    }
    if (half == 0) {
      P1[((size_t)c * NSLOT + 24) * NFEAT + f] = u2p;
      P1[((size_t)c * NSLOT + 25) * NFEAT + f] = u2a;
      P1[((size_t)c * NSLOT + 26) * NFEAT + f] = npos;
      P1[((size_t)c * NSLOT + 27) * NFEAT + f] = 0.0f;
    }
  } else {
    // ---- exact general path: 3 proposals per half, direct sums ----
    float ga_p[3], ga_n[3], gs_p[3], gs_n[3], gt_p[3], gt_n[3];
#pragma unroll
    for (int m = 0; m < 3; ++m) {
      const int j = half * 3 + m;
      float dp = (j == 0) ? 0.0f : 0.1f * rp[f * 10 + 2 * (j - 1)];
      float dn = (j == 0) ? 0.0f : -0.1f * rp[f * 10 + 2 * (j - 1) + 1];
      float a1 = L1 + dp;
      float a2 = An + dn;
      bool z1 = fabsf(a1) < F_EPS;
      bool z2 = fabsf(a2) < F_EPS;
      ga_p[m] = z1 ? 0.0f : a1;
      gs_p[m] = z1 ? 0.0f : 1.0f / a1;
      gt_p[m] = z1 ? F_LN2 : 0.0f;
      ga_n[m] = z2 ? 0.0f : a2;
      gs_n[m] = z2 ? 0.0f : -1.0f / a2;
      gt_n[m] = z2 ? -F_LN2 : 0.0f;
    }
    float as[3], aq[3];
#pragma unroll
    for (int m = 0; m < 3; ++m) { as[m] = 0.f; aq[m] = 0.f; }
    float u2p = 0.f, u2a = 0.f;
    for (int i = 0; i < rpt; ++i) {
      float v = xp[(size_t)i * NFEAT];
      bool pos = v >= 0.0f;
      float u2 = FAST_LOG2(1.0f + fabsf(v));
      u2a += u2;
      u2p += pos ? u2 : 0.0f;
#pragma unroll
      for (int m = 0; m < 3; ++m) {
        float a  = pos ? ga_p[m] : ga_n[m];
        float s  = pos ? gs_p[m] : gs_n[m];
        float tt = pos ? gt_p[m] : gt_n[m];
        float e = FAST_EXP2(a * u2);
        float y = fmaf(tt, u2, fmaf(s, e, -s));
        as[m] += y;
        aq[m] = fmaf(y, y, aq[m]);
      }
    }
#pragma unroll
    for (int m = 0; m < 3; ++m) {
      const int j = half * 3 + m;
      P1[((size_t)c * NSLOT + j) * NFEAT + f]      = as[m];
      P1[((size_t)c * NSLOT + 6 + j) * NFEAT + f]  = aq[m];
      P1[((size_t)c * NSLOT + 12 + j) * NFEAT + f] = 0.0f;
      P1[((size_t)c * NSLOT + 18 + j) * NFEAT + f] = 0.0f;
    }
    if (half == 0) {
      P1[((size_t)c * NSLOT + 24) * NFEAT + f] = u2p;
      P1[((size_t)c * NSLOT + 25) * NFEAT + f] = u2a;
      P1[((size_t)c * NSLOT + 26) * NFEAT + f] = 0.0f;
      P1[((size_t)c * NSLOT + 27) * NFEAT + f] = 1.0f;
    }
  }
}

// Stage A reduce: block (k, cg): S2[(k*RGRP+cg)*NFEAT+f] = sum over c-subrange.
__global__ __launch_bounds__(256) void k_reduce_S(
    const float* __restrict__ P1, double* __restrict__ S2, int CHv)
{
  const int k = blockIdx.x / RGRP;
  const int cg = blockIdx.x % RGRP;
  const int f = threadIdx.x;
  const int per = CHv / RGRP;
  const int c0 = cg * per;
  double a0 = 0.0, a1 = 0.0, a2 = 0.0, a3 = 0.0;
  for (int c = c0; c < c0 + per; c += 4) {
    a0 += (double)P1[((size_t)(c + 0) * NSLOT + k) * NFEAT + f];
    a1 += (double)P1[((size_t)(c + 1) * NSLOT + k) * NFEAT + f];
    a2 += (double)P1[((size_t)(c + 2) * NSLOT + k) * NFEAT + f];
    a3 += (double)P1[((size_t)(c + 3) * NSLOT + k) * NFEAT + f];
  }
  S2[((size_t)k * RGRP + cg) * NFEAT + f] = (a0 + a1) + (a2 + a3);
}

// One thread per feature: reconstruct 6 scores in f64, min, tie-average.
__global__ __launch_bounds__(256) void k_pick(
    const double* __restrict__ S2, const float* __restrict__ lam1,
    const float* __restrict__ lam2, const float* __restrict__ rp,
    float* __restrict__ bestL, int* __restrict__ tied,
    double* __restrict__ bitsF, int* __restrict__ anyTied)
{
  const int f = threadIdx.x;
  if (f == 0) *anyTied = 0;
  double s[NSLOT];
#pragma unroll
  for (int k = 0; k < NSLOT; ++k) {
    double a = 0.0;
#pragma unroll
    for (int cg = 0; cg < RGRP; ++cg)
      a += S2[((size_t)k * RGRP + cg) * NFEAT + f];
    s[k] = a;
  }
  const double n = (double)NROWS;
  const bool direct = s[27] > 0.5;
  const double npos = s[26];
  const double nneg = n - npos;
  const double sup = s[24];
  const double sun = s[25] - s[24];
  const float L1 = lam1[f], L2 = lam2[f];
  const double dAn = 2.0 - (double)L2;   // f64 negative-branch center
  double scores[6], al1[6], al2[6];
#pragma unroll
  for (int j = 0; j < 6; ++j) {
    float l1 = (j == 0) ? L1 : L1 + 0.1f * rp[f * 10 + 2 * (j - 1)];
    float l2 = (j == 0) ? L2 : L2 + 0.1f * rp[f * 10 + 2 * (j - 1) + 1];
    al1[j] = (double)l1; al2[j] = (double)l2;
    bool z1 = fabsf(l1) < F_EPS;
    bool z2 = fabsf(l2 - 2.0f) < F_EPS;
    double ccp = z1 ? -1.0 : (double)l1 - 1.0;
    double ccn = z2 ? -1.0 : 1.0 - (double)l2;
    double ljb = ccp * sup + ccn * sun;

    double sum_y, sum_y2;
    if (direct) {
      sum_y  = s[j];
      sum_y2 = s[6 + j];
    } else {
      const double dp  = (double)l1 - (double)L1;
      const double dnn = (2.0 - (double)l2) - dAn;
      const double sp = 1.0 / ((double)L1 + dp);
      const double sn = -1.0 / (dAn + dnn);
      const double Ep  = horner_exp(&s[0],  dp);
      const double Ep2 = horner_exp(&s[6],  2.0 * dp);
      const double En  = horner_exp(&s[12], dnn);
      const double En2 = horner_exp(&s[18], 2.0 * dnn);
      sum_y  = sp * (Ep - npos) + sn * (En - nneg);
      sum_y2 = sp * sp * (Ep2 - 2.0 * Ep + npos)
             + sn * sn * (En2 - 2.0 * En + nneg);
    }
    double mean = sum_y / n;
    double var = sum_y2 / n - mean * mean;
    var = var > 1e-12 ? var : 1e-12;
    scores[j] = n * (D_HALF_LOG2_2PIE + 0.5 * log2(var)) + ljb + D_LAMBDA_BITS;
  }
  double mn = scores[0];
#pragma unroll
  for (int j = 1; j < 6; ++j) mn = scores[j] < mn ? scores[j] : mn;
  double wsum = 0.0, b1 = 0.0, b2 = 0.0;
#pragma unroll
  for (int j = 0; j < 6; ++j) {
    double w = (scores[j] == mn) ? 1.0 : 0.0;
    wsum += w; b1 += w * al1[j]; b2 += w * al2[j];
  }
  bestL[2 * f]     = (float)(b1 / wsum);
  bestL[2 * f + 1] = (float)(b2 / wsum);
  const int isTied = (wsum > 1.5) ? 1 : 0;
  tied[f] = isTied;
  if (isTied) atomicOr(anyTied, 1);
  bitsF[f] = mn;   // unique min: identical to re-evaluating at best lambda
}

// Fallback pass 2 (only if some feature tied: averaged lambda is new).
__global__ __launch_bounds__(256) void k_pass2(
    const float* __restrict__ x, const float* __restrict__ bestL,
    const int* __restrict__ anyTied, float* __restrict__ P2)
{
  if (*anyTied == 0) return;
  const int t = threadIdx.x;
  const int c = blockIdx.x;
  const int rpt = NROWS / CH2;   // 128
  const float l1 = bestL[2 * t], l2 = bestL[2 * t + 1];
  const bool z1 = fabsf(l1) < F_EPS;
  const bool z2 = fabsf(l2 - 2.0f) < F_EPS;
  const float tm = 2.0f - l2;
  const float a_p = z1 ? 0.f : l1,  s_pv = z1 ? 0.f : 1.f / l1,  t_pv = z1 ? F_LN2 : 0.f;
  const float a_n = z2 ? 0.f : tm,  s_nv = z2 ? 0.f : -1.f / tm, t_nv = z2 ? -F_LN2 : 0.f;

  float sy = 0.f, sq = 0.f;
  const float* xp = x + (size_t)c * rpt * NFEAT + t;
  for (int i = 0; i < rpt; ++i) {
    float v = xp[(size_t)i * NFEAT];
    bool pos = v >= 0.0f;
    float u2 = FAST_LOG2(1.0f + fabsf(v));
    float a  = pos ? a_p : a_n;
    float s  = pos ? s_pv : s_nv;
    float tt = pos ? t_pv : t_nv;
    float e = FAST_EXP2(a * u2);
    float y = fmaf(tt, u2, fmaf(s, e, -s));
    sy += y;
    sq = fmaf(y, y, sq);
  }
  P2[((size_t)c * 2 + 0) * NFEAT + t] = sy;
  P2[((size_t)c * 2 + 1) * NFEAT + t] = sq;
}

__global__ __launch_bounds__(64) void k_featbits(
    const float* __restrict__ P1, const float* __restrict__ P2,
    const float* __restrict__ bestL, const int* __restrict__ tied,
    double* __restrict__ bitsF, int CHv)
{
  const int f = blockIdx.x;
  if (!tied[f]) return;
  const int lane = threadIdx.x;
  double s0 = 0.0, s1 = 0.0, sup = 0.0, sua = 0.0;
  for (int c = lane; c < CH2; c += 64) {
    s0 += (double)P2[((size_t)c * 2 + 0) * NFEAT + f];
    s1 += (double)P2[((size_t)c * 2 + 1) * NFEAT + f];
  }
  for (int c = lane; c < CHv; c += 64) {
    sup += (double)P1[((size_t)c * NSLOT + 24) * NFEAT + f];
    sua += (double)P1[((size_t)c * NSLOT + 25) * NFEAT + f];
  }
  s0 = wave_reduce_add(s0); s1 = wave_reduce_add(s1);
  sup = wave_reduce_add(sup); sua = wave_reduce_add(sua);
  if (lane == 0) {
    const float l1 = bestL[2 * f], l2 = bestL[2 * f + 1];
    bool z1 = fabsf(l1) < F_EPS;
    bool z2 = fabsf(l2 - 2.0f) < F_EPS;
    double ccp = z1 ? -1.0 : (double)l1 - 1.0;
    double ccn = z2 ? -1.0 : 1.0 - (double)l2;
    double ljb = ccp * sup + ccn * (sua - sup);
    const double n = (double)NROWS;
    double mean = s0 / n;
    double var = s1 / n - mean * mean;
    var = var > 1e-12 ? var : 1e-12;
    bitsF[f] = n * (D_HALF_LOG2_2PIE + 0.5 * log2(var)) + ljb + D_LAMBDA_BITS;
  }
}

__global__ __launch_bounds__(256) void k_final(
    const double* __restrict__ bitsF, const double* __restrict__ pSums,
    float* __restrict__ out)
{
  __shared__ double l[4];
  double s = bitsF[threadIdx.x];
  s = wave_reduce_add(s);
  int w = threadIdx.x >> 6;
  if ((threadIdx.x & 63) == 0) l[w] = s;
  __syncthreads();
  if (threadIdx.x == 0) {
    double data = l[0] + l[1] + l[2] + l[3];
    const double n = (double)PCOUNT;
    double mean = pSums[0] / n;
    double var = pSums[1] / n - mean * mean;
    var = var > 1e-12 ? var : 1e-12;
    double model = n * (D_HALF_LOG2_2PIE + 0.5 * log2(var)) + D_LAMBDA_BITS;
    out[0] = (float)(data + model);
  }
}

extern "C" void kernel_launch(void* const* d_in, const int* in_sizes, int n_in,
                              void* d_out, int out_size, void* d_ws, size_t ws_size,
                              hipStream_t stream)
{
  const float* x      = (const float*)d_in[0];
  const float* lam1   = (const float*)d_in[1];
  const float* lam2   = (const float*)d_in[2];
  const float* rp     = (const float*)d_in[3];
  const float* params = (const float*)d_in[4];

  char* ws = (char*)d_ws;
  double* pSums  = (double*)ws;                 // 16 B   -> 16
  float*  bestL  = (float*)(ws + 16);           // 2048   -> 2064
  double* bitsF  = (double*)(ws + 2064);        // 2048   -> 4112
  int*    tied   = (int*)(ws + 4112);           // 1024   -> 5136
  int*    anyT   = (int*)(ws + 5136);           // 4      -> pad 5152
  double* S2     = (double*)(ws + 5152);        // 28*16*256*8 = 917504 -> 922656
  float*  P1     = (float*)(ws + 922656);

  // chunk count: CHv=1024, fall back if ws small
  int CHv = 1024;
  while (CHv > 128) {
    size_t need = 922656 + (size_t)CHv * NSLOT * NFEAT * 4
                         + (size_t)CH2 * 2 * NFEAT * 4;
    if (need <= ws_size) break;
    CHv >>= 1;
  }
  float* P2 = (float*)(ws + 922656 + (size_t)CHv * NSLOT * NFEAT * 4);
  int rpt = NROWS / CHv;   // 64 at CHv=1024

  (void)hipMemsetAsync(pSums, 0, 16, stream);
  k_pass1<<<CHv + PBLK, 512, 0, stream>>>(x, lam1, lam2, rp, params, P1,
                                          pSums, CHv, rpt);
  k_reduce_S<<<NSLOT * RGRP, 256, 0, stream>>>(P1, S2, CHv);
  k_pick<<<1, 256, 0, stream>>>(S2, lam1, lam2, rp, bestL, tied, bitsF, anyT);
  k_pass2<<<CH2, 256, 0, stream>>>(x, bestL, anyT, P2);
  k_featbits<<<NFEAT, 64, 0, stream>>>(P1, P2, bestL, tied, bitsF, CHv);
  k_final<<<1, 256, 0, stream>>>(bitsF, pSums, (float*)d_out);
}

// Round 23
// 79.961 us; speedup vs baseline: 1.0229x; 1.0037x over previous
//
#include <hip/hip_runtime.h>
#include <math.h>

#define NFEAT 256
#define NROWS 65536
#define PCOUNT 4194304
#define PBLK 64                      // param-reduce blocks appended to pass1 grid
#define CH2 512                      // pass2 fallback chunks
#define RGRP 16                      // reduce_S c-groups
#define NSLOT 28                     // P1 slots per chunk per feature
#define F_EPS 5.9604645e-07f         // float32 eps * 5
#define F_LN2 0.69314718056f
#define DELTA_MAX 0.45f              // poly-validity gate on |0.1*rp|

#define FAST_LOG2(v) __builtin_log2f(v)   // v_log_f32
#define FAST_EXP2(v) __builtin_exp2f(v)   // v_exp_f32

typedef float v2f __attribute__((ext_vector_type(2)));

constexpr double D_HALF_LOG2_2PIE = 0.5 * 2.8378770664093453 / 0.6931471805599453;
constexpr double D_LAMBDA_BITS = 13.287712379549449; // 2*log2(100)

__device__ inline double wave_reduce_add(double v) {
  for (int o = 32; o > 0; o >>= 1) v += __shfl_down(v, o, 64);
  return v;
}

// sum_k d^k/k! * m[k], k=0..5 (Horner)
__device__ inline double horner_exp(const double* m, double d) {
  double p = m[5] * (1.0 / 120.0);
  p = p * d + m[4] * (1.0 / 24.0);
  p = p * d + m[3] * (1.0 / 6.0);
  p = p * d + m[2] * 0.5;
  p = p * d + m[1];
  p = p * d + m[0];
  return p;
}

// ---------------------------------------------------------------------------
// Pass 1 (split-moment, packed-FP32): 512-thread blocks, thread = (f=tid&255,
// half=tid>>8). Both halves scan the SAME rows; half h owns Taylor orders
// k=3h..3h+2. Moment fmas packed as float2 (pos,neg) lanes.
// launch_bounds (512,8): r22 measured VGPR=32 / Occupancy 54% -- the (512,4)
// bound capped waves at 16/CU (2nd arg is waves/EU!). 64-reg budget fits the
// 32-reg kernel, doubles residency ceiling. (r11's (512,8) spill was a
// ~90-reg kernel; this one is 32.)
// Moments: M_k = sum B*q^k, M2_k = sum B^2*q^k; B = exp2(center*u),
// q = u*ln2, u = log2(1+|x|). Reconstruction per-feature in f64 in k_pick
// (5th-order Taylor, same truncation as r13 -> absmax 0.0).
// Slots: 0..5 Mp(k), 6..11 Mp2, 12..17 Mn, 18..23 Mn2, 24 u2p, 25 u2a,
// 26 npos, 27 flag (1 = direct sums from exact general path; half h owns
// j=3h..3h+2 there).
// Blocks >= CHv: parameter tensor reduction (overlapped, memory-bound).
// ---------------------------------------------------------------------------
__global__ __launch_bounds__(512, 8) void k_pass1(
    const float* __restrict__ x, const float* __restrict__ lam1,
    const float* __restrict__ lam2, const float* __restrict__ rp,
    const float* __restrict__ params, float* __restrict__ P1,
    double* __restrict__ pSums, int CHv, int rpt)
{
  const int c = blockIdx.x;
  const int tid = threadIdx.x;

  if (c >= CHv) {
    // ---- parameter tensor partial reduction ----
    __shared__ double lred[2][8];
    const int b = c - CHv;
    const float4* p4 = (const float4*)params;
    double s = 0.0, q = 0.0;
    for (int i = b * 512 + tid; i < PCOUNT / 4; i += PBLK * 512) {
      float4 v = p4[i];
      s += (double)v.x + (double)v.y + (double)v.z + (double)v.w;
      q += (double)v.x * v.x + (double)v.y * v.y
         + (double)v.z * v.z + (double)v.w * v.w;
    }
    s = wave_reduce_add(s); q = wave_reduce_add(q);
    const int w = tid >> 6;
    if ((tid & 63) == 0) { lred[0][w] = s; lred[1][w] = q; }
    __syncthreads();
    if (tid == 0) {
      double S = 0.0, Q = 0.0;
#pragma unroll
      for (int i = 0; i < 8; ++i) { S += lred[0][i]; Q += lred[1][i]; }
      atomicAdd(&pSums[0], S);
      atomicAdd(&pSums[1], Q);
    }
    return;
  }

  const int f = tid & 255;
  const int half = tid >> 8;           // wave-uniform
  __shared__ int bad;
  if (tid == 0) bad = 0;
  __syncthreads();

  const float L1 = lam1[f], L2 = lam2[f];
  const float An = 2.0f - L2;          // negative-branch center
  {
    bool b = (fabsf(L1) < F_EPS) || (fabsf(An) < F_EPS);
#pragma unroll
    for (int j = 1; j < 6; ++j) {
      float dp = 0.1f * rp[f * 10 + 2 * (j - 1)];
      float dn = -0.1f * rp[f * 10 + 2 * (j - 1) + 1];
      b = b || (fabsf(L1 + dp) < F_EPS) || (fabsf(An + dn) < F_EPS)
            || (fabsf(dp) > DELTA_MAX) || (fabsf(dn) > DELTA_MAX);
    }
    if (b) bad = 1;  // benign same-value race
  }
  __syncthreads();

  const float* xp = x + (size_t)c * rpt * NFEAT + f;

  if (bad == 0) {
    // ---- moment path: 6 float2 accumulators (12 regs) + half0 scalars ----
    v2f MB[3], MC[3];                  // MB[m]=(Mp_k, Mn_k), MC[m]=(Mp2_k, Mn2_k)
#pragma unroll
    for (int m = 0; m < 3; ++m) { MB[m] = (v2f)(0.f); MC[m] = (v2f)(0.f); }
    float u2p = 0.f, u2a = 0.f, npos = 0.f;

#pragma unroll 4
    for (int i = 0; i < rpt; ++i) {
      const float v = xp[(size_t)i * NFEAT];
      const bool pos = v >= 0.0f;
      const float u = FAST_LOG2(1.0f + fabsf(v));
      if (half == 0) {                 // wave-uniform branch
        u2a += u;
        u2p += pos ? u : 0.0f;
        npos += pos ? 1.0f : 0.0f;
      }
      const float q = u * F_LN2;
      const float B = FAST_EXP2((pos ? L1 : An) * u);
      const float B2 = B * B;
      const v2f BV = pos ? (v2f){B, 0.f}  : (v2f){0.f, B};
      const v2f CV = pos ? (v2f){B2, 0.f} : (v2f){0.f, B2};
      float w0;
      if (half == 0) w0 = 1.0f;
      else { const float q2 = q * q; w0 = q2 * q; }
      const float w1 = w0 * q;
      const float w2 = w1 * q;
      const v2f W0 = (v2f){w0, w0};
      const v2f W1 = (v2f){w1, w1};
      const v2f W2 = (v2f){w2, w2};
      MB[0] = __builtin_elementwise_fma(BV, W0, MB[0]);
      MB[1] = __builtin_elementwise_fma(BV, W1, MB[1]);
      MB[2] = __builtin_elementwise_fma(BV, W2, MB[2]);
      MC[0] = __builtin_elementwise_fma(CV, W0, MC[0]);
      MC[1] = __builtin_elementwise_fma(CV, W1, MC[1]);
      MC[2] = __builtin_elementwise_fma(CV, W2, MC[2]);
    }
    // store: Mp -> 0..5, Mp2 -> 6..11, Mn -> 12..17, Mn2 -> 18..23
#pragma unroll
    for (int m = 0; m < 3; ++m) {
      const int k = half * 3 + m;
      P1[((size_t)c * NSLOT + k) * NFEAT + f]      = MB[m].x;
      P1[((size_t)c * NSLOT + 6 + k) * NFEAT + f]  = MC[m].x;
      P1[((size_t)c * NSLOT + 12 + k) * NFEAT + f] = MB[m].y;
      P1[((size_t)c * NSLOT + 18 + k) * NFEAT + f] = MC[m].y;
    }
    if (half == 0) {
      P1[((size_t)c * NSLOT + 24) * NFEAT + f] = u2p;
      P1[((size_t)c * NSLOT + 25) * NFEAT + f] = u2a;
      P1[((size_t)c * NSLOT + 26) * NFEAT + f] = npos;
      P1[((size_t)c * NSLOT + 27) * NFEAT + f] = 0.0f;
    }
  } else {
    // ---- exact general path: 3 proposals per half, direct sums ----
    float ga_p[3], ga_n[3], gs_p[3], gs_n[3], gt_p[3], gt_n[3];
#pragma unroll
    for (int m = 0; m < 3; ++m) {
      const int j = half * 3 + m;
      float dp = (j == 0) ? 0.0f : 0.1f * rp[f * 10 + 2 * (j - 1)];
      float dn = (j == 0) ? 0.0f : -0.1f * rp[f * 10 + 2 * (j - 1) + 1];
      float a1 = L1 + dp;
      float a2 = An + dn;
      bool z1 = fabsf(a1) < F_EPS;
      bool z2 = fabsf(a2) < F_EPS;
      ga_p[m] = z1 ? 0.0f : a1;
      gs_p[m] = z1 ? 0.0f : 1.0f / a1;
      gt_p[m] = z1 ? F_LN2 : 0.0f;
      ga_n[m] = z2 ? 0.0f : a2;
      gs_n[m] = z2 ? 0.0f : -1.0f / a2;
      gt_n[m] = z2 ? -F_LN2 : 0.0f;
    }
    float as[3], aq[3];
#pragma unroll
    for (int m = 0; m < 3; ++m) { as[m] = 0.f; aq[m] = 0.f; }
    float u2p = 0.f, u2a = 0.f;
    for (int i = 0; i < rpt; ++i) {
      float v = xp[(size_t)i * NFEAT];
      bool pos = v >= 0.0f;
      float u2 = FAST_LOG2(1.0f + fabsf(v));
      u2a += u2;
      u2p += pos ? u2 : 0.0f;
#pragma unroll
      for (int m = 0; m < 3; ++m) {
        float a  = pos ? ga_p[m] : ga_n[m];
        float s  = pos ? gs_p[m] : gs_n[m];
        float tt = pos ? gt_p[m] : gt_n[m];
        float e = FAST_EXP2(a * u2);
        float y = fmaf(tt, u2, fmaf(s, e, -s));
        as[m] += y;
        aq[m] = fmaf(y, y, aq[m]);
      }
    }
#pragma unroll
    for (int m = 0; m < 3; ++m) {
      const int j = half * 3 + m;
      P1[((size_t)c * NSLOT + j) * NFEAT + f]      = as[m];
      P1[((size_t)c * NSLOT + 6 + j) * NFEAT + f]  = aq[m];
      P1[((size_t)c * NSLOT + 12 + j) * NFEAT + f] = 0.0f;
      P1[((size_t)c * NSLOT + 18 + j) * NFEAT + f] = 0.0f;
    }
    if (half == 0) {
      P1[((size_t)c * NSLOT + 24) * NFEAT + f] = u2p;
      P1[((size_t)c * NSLOT + 25) * NFEAT + f] = u2a;
      P1[((size_t)c * NSLOT + 26) * NFEAT + f] = 0.0f;
      P1[((size_t)c * NSLOT + 27) * NFEAT + f] = 1.0f;
    }
  }
}

// Stage A reduce: block (k, cg): S2[(k*RGRP+cg)*NFEAT+f] = sum over c-subrange.
__global__ __launch_bounds__(256) void k_reduce_S(
    const float* __restrict__ P1, double* __restrict__ S2, int CHv)
{
  const int k = blockIdx.x / RGRP;
  const int cg = blockIdx.x % RGRP;
  const int f = threadIdx.x;
  const int per = CHv / RGRP;
  const int c0 = cg * per;
  double a0 = 0.0, a1 = 0.0, a2 = 0.0, a3 = 0.0;
  for (int c = c0; c < c0 + per; c += 4) {
    a0 += (double)P1[((size_t)(c + 0) * NSLOT + k) * NFEAT + f];
    a1 += (double)P1[((size_t)(c + 1) * NSLOT + k) * NFEAT + f];
    a2 += (double)P1[((size_t)(c + 2) * NSLOT + k) * NFEAT + f];
    a3 += (double)P1[((size_t)(c + 3) * NSLOT + k) * NFEAT + f];
  }
  S2[((size_t)k * RGRP + cg) * NFEAT + f] = (a0 + a1) + (a2 + a3);
}

// One thread per feature: reconstruct 6 scores in f64, min, tie-average.
__global__ __launch_bounds__(256) void k_pick(
    const double* __restrict__ S2, const float* __restrict__ lam1,
    const float* __restrict__ lam2, const float* __restrict__ rp,
    float* __restrict__ bestL, int* __restrict__ tied,
    double* __restrict__ bitsF, int* __restrict__ anyTied)
{
  const int f = threadIdx.x;
  if (f == 0) *anyTied = 0;
  double s[NSLOT];
#pragma unroll
  for (int k = 0; k < NSLOT; ++k) {
    double a = 0.0;
#pragma unroll
    for (int cg = 0; cg < RGRP; ++cg)
      a += S2[((size_t)k * RGRP + cg) * NFEAT + f];
    s[k] = a;
  }
  const double n = (double)NROWS;
  const bool direct = s[27] > 0.5;
  const double npos = s[26];
  const double nneg = n - npos;
  const double sup = s[24];
  const double sun = s[25] - s[24];
  const float L1 = lam1[f], L2 = lam2[f];
  const double dAn = 2.0 - (double)L2;   // f64 negative-branch center
  double scores[6], al1[6], al2[6];
#pragma unroll
  for (int j = 0; j < 6; ++j) {
    float l1 = (j == 0) ? L1 : L1 + 0.1f * rp[f * 10 + 2 * (j - 1)];
    float l2 = (j == 0) ? L2 : L2 + 0.1f * rp[f * 10 + 2 * (j - 1) + 1];
    al1[j] = (double)l1; al2[j] = (double)l2;
    bool z1 = fabsf(l1) < F_EPS;
    bool z2 = fabsf(l2 - 2.0f) < F_EPS;
    double ccp = z1 ? -1.0 : (double)l1 - 1.0;
    double ccn = z2 ? -1.0 : 1.0 - (double)l2;
    double ljb = ccp * sup + ccn * sun;

    double sum_y, sum_y2;
    if (direct) {
      sum_y  = s[j];
      sum_y2 = s[6 + j];
    } else {
      const double dp  = (double)l1 - (double)L1;
      const double dnn = (2.0 - (double)l2) - dAn;
      const double sp = 1.0 / ((double)L1 + dp);
      const double sn = -1.0 / (dAn + dnn);
      const double Ep  = horner_exp(&s[0],  dp);
      const double Ep2 = horner_exp(&s[6],  2.0 * dp);
      const double En  = horner_exp(&s[12], dnn);
      const double En2 = horner_exp(&s[18], 2.0 * dnn);
      sum_y  = sp * (Ep - npos) + sn * (En - nneg);
      sum_y2 = sp * sp * (Ep2 - 2.0 * Ep + npos)
             + sn * sn * (En2 - 2.0 * En + nneg);
    }
    double mean = sum_y / n;
    double var = sum_y2 / n - mean * mean;
    var = var > 1e-12 ? var : 1e-12;
    scores[j] = n * (D_HALF_LOG2_2PIE + 0.5 * log2(var)) + ljb + D_LAMBDA_BITS;
  }
  double mn = scores[0];
#pragma unroll
  for (int j = 1; j < 6; ++j) mn = scores[j] < mn ? scores[j] : mn;
  double wsum = 0.0, b1 = 0.0, b2 = 0.0;
#pragma unroll
  for (int j = 0; j < 6; ++j) {
    double w = (scores[j] == mn) ? 1.0 : 0.0;
    wsum += w; b1 += w * al1[j]; b2 += w * al2[j];
  }
  bestL[2 * f]     = (float)(b1 / wsum);
  bestL[2 * f + 1] = (float)(b2 / wsum);
  const int isTied = (wsum > 1.5) ? 1 : 0;
  tied[f] = isTied;
  if (isTied) atomicOr(anyTied, 1);
  bitsF[f] = mn;   // unique min: identical to re-evaluating at best lambda
}

// Fallback pass 2 (only if some feature tied: averaged lambda is new).
__global__ __launch_bounds__(256) void k_pass2(
    const float* __restrict__ x, const float* __restrict__ bestL,
    const int* __restrict__ anyTied, float* __restrict__ P2)
{
  if (*anyTied == 0) return;
  const int t = threadIdx.x;
  const int c = blockIdx.x;
  const int rpt = NROWS / CH2;   // 128
  const float l1 = bestL[2 * t], l2 = bestL[2 * t + 1];
  const bool z1 = fabsf(l1) < F_EPS;
  const bool z2 = fabsf(l2 - 2.0f) < F_EPS;
  const float tm = 2.0f - l2;
  const float a_p = z1 ? 0.f : l1,  s_pv = z1 ? 0.f : 1.f / l1,  t_pv = z1 ? F_LN2 : 0.f;
  const float a_n = z2 ? 0.f : tm,  s_nv = z2 ? 0.f : -1.f / tm, t_nv = z2 ? -F_LN2 : 0.f;

  float sy = 0.f, sq = 0.f;
  const float* xp = x + (size_t)c * rpt * NFEAT + t;
  for (int i = 0; i < rpt; ++i) {
    float v = xp[(size_t)i * NFEAT];
    bool pos = v >= 0.0f;
    float u2 = FAST_LOG2(1.0f + fabsf(v));
    float a  = pos ? a_p : a_n;
    float s  = pos ? s_pv : s_nv;
    float tt = pos ? t_pv : t_nv;
    float e = FAST_EXP2(a * u2);
    float y = fmaf(tt, u2, fmaf(s, e, -s));
    sy += y;
    sq = fmaf(y, y, sq);
  }
  P2[((size_t)c * 2 + 0) * NFEAT + t] = sy;
  P2[((size_t)c * 2 + 1) * NFEAT + t] = sq;
}

__global__ __launch_bounds__(64) void k_featbits(
    const float* __restrict__ P1, const float* __restrict__ P2,
    const float* __restrict__ bestL, const int* __restrict__ tied,
    double* __restrict__ bitsF, int CHv)
{
  const int f = blockIdx.x;
  if (!tied[f]) return;
  const int lane = threadIdx.x;
  double s0 = 0.0, s1 = 0.0, sup = 0.0, sua = 0.0;
  for (int c = lane; c < CH2; c += 64) {
    s0 += (double)P2[((size_t)c * 2 + 0) * NFEAT + f];
    s1 += (double)P2[((size_t)c * 2 + 1) * NFEAT + f];
  }
  for (int c = lane; c < CHv; c += 64) {
    sup += (double)P1[((size_t)c * NSLOT + 24) * NFEAT + f];
    sua += (double)P1[((size_t)c * NSLOT + 25) * NFEAT + f];
  }
  s0 = wave_reduce_add(s0); s1 = wave_reduce_add(s1);
  sup = wave_reduce_add(sup); sua = wave_reduce_add(sua);
  if (lane == 0) {
    const float l1 = bestL[2 * f], l2 = bestL[2 * f + 1];
    bool z1 = fabsf(l1) < F_EPS;
    bool z2 = fabsf(l2 - 2.0f) < F_EPS;
    double ccp = z1 ? -1.0 : (double)l1 - 1.0;
    double ccn = z2 ? -1.0 : 1.0 - (double)l2;
    double ljb = ccp * sup + ccn * (sua - sup);
    const double n = (double)NROWS;
    double mean = s0 / n;
    double var = s1 / n - mean * mean;
    var = var > 1e-12 ? var : 1e-12;
    bitsF[f] = n * (D_HALF_LOG2_2PIE + 0.5 * log2(var)) + ljb + D_LAMBDA_BITS;
  }
}

__global__ __launch_bounds__(256) void k_final(
    const double* __restrict__ bitsF, const double* __restrict__ pSums,
    float* __restrict__ out)
{
  __shared__ double l[4];
  double s = bitsF[threadIdx.x];
  s = wave_reduce_add(s);
  int w = threadIdx.x >> 6;
  if ((threadIdx.x & 63) == 0) l[w] = s;
  __syncthreads();
  if (threadIdx.x == 0) {
    double data = l[0] + l[1] + l[2] + l[3];
    const double n = (double)PCOUNT;
    double mean = pSums[0] / n;
    double var = pSums[1] / n - mean * mean;
    var = var > 1e-12 ? var : 1e-12;
    double model = n * (D_HALF_LOG2_2PIE + 0.5 * log2(var)) + D_LAMBDA_BITS;
    out[0] = (float)(data + model);
  }
}

extern "C" void kernel_launch(void* const* d_in, const int* in_sizes, int n_in,
                              void* d_out, int out_size, void* d_ws, size_t ws_size,
                              hipStream_t stream)
{
  const float* x      = (const float*)d_in[0];
  const float* lam1   = (const float*)d_in[1];
  const float* lam2   = (const float*)d_in[2];
  const float* rp     = (const float*)d_in[3];
  const float* params = (const float*)d_in[4];

  char* ws = (char*)d_ws;
  double* pSums  = (double*)ws;                 // 16 B   -> 16
  float*  bestL  = (float*)(ws + 16);           // 2048   -> 2064
  double* bitsF  = (double*)(ws + 2064);        // 2048   -> 4112
  int*    tied   = (int*)(ws + 4112);           // 1024   -> 5136
  int*    anyT   = (int*)(ws + 5136);           // 4      -> pad 5152
  double* S2     = (double*)(ws + 5152);        // 28*16*256*8 = 917504 -> 922656
  float*  P1     = (float*)(ws + 922656);

  // chunk count: CHv=1024, fall back if ws small
  int CHv = 1024;
  while (CHv > 128) {
    size_t need = 922656 + (size_t)CHv * NSLOT * NFEAT * 4
                         + (size_t)CH2 * 2 * NFEAT * 4;
    if (need <= ws_size) break;
    CHv >>= 1;
  }
  float* P2 = (float*)(ws + 922656 + (size_t)CHv * NSLOT * NFEAT * 4);
  int rpt = NROWS / CHv;   // 64 at CHv=1024

  (void)hipMemsetAsync(pSums, 0, 16, stream);
  k_pass1<<<CHv + PBLK, 512, 0, stream>>>(x, lam1, lam2, rp, params, P1,
                                          pSums, CHv, rpt);
  k_reduce_S<<<NSLOT * RGRP, 256, 0, stream>>>(P1, S2, CHv);
  k_pick<<<1, 256, 0, stream>>>(S2, lam1, lam2, rp, bestL, tied, bitsF, anyT);
  k_pass2<<<CH2, 256, 0, stream>>>(x, bestL, anyT, P2);
  k_featbits<<<NFEAT, 64, 0, stream>>>(P1, P2, bestL, tied, bitsF, CHv);
  k_final<<<1, 256, 0, stream>>>(bitsF, pSums, (float*)d_out);
}

// Round 24
// 70.705 us; speedup vs baseline: 1.1568x; 1.1309x over previous
//
#include <hip/hip_runtime.h>
#include <math.h>

#define NFEAT 256
#define NROWS 65536
#define PCOUNT 4194304
#define PBLK 64                      // param-reduce blocks appended to pass1 grid
#define CH2 512                      // pass2 fallback chunks
#define RGRP 16                      // reduce_S c-groups
#define NSLOT 28                     // P1 slots per chunk per feature
#define F_EPS 5.9604645e-07f         // float32 eps * 5
#define F_LN2 0.69314718056f
#define DELTA_MAX 0.45f              // poly-validity gate on |0.1*rp|

#define FAST_LOG2(v) __builtin_log2f(v)   // v_log_f32
#define FAST_EXP2(v) __builtin_exp2f(v)   // v_exp_f32

constexpr double D_HALF_LOG2_2PIE = 0.5 * 2.8378770664093453 / 0.6931471805599453;
constexpr double D_LAMBDA_BITS = 13.287712379549449; // 2*log2(100)

__device__ inline double wave_reduce_add(double v) {
  for (int o = 32; o > 0; o >>= 1) v += __shfl_down(v, o, 64);
  return v;
}

// sum_k d^k/k! * m[k], k=0..5 (Horner)
__device__ inline double horner_exp(const double* m, double d) {
  double p = m[5] * (1.0 / 120.0);
  p = p * d + m[4] * (1.0 / 24.0);
  p = p * d + m[3] * (1.0 / 6.0);
  p = p * d + m[2] * 0.5;
  p = p * d + m[1];
  p = p * d + m[0];
  return p;
}

// ---------------------------------------------------------------------------
// Pass 1 (r16 moment form + deeper residency): 256-thread blocks, thread t =
// feature t; block c owns rows [c*rpt,(c+1)*rpt). SINGLE read of x (lowest
// busy-time variant measured: 19us at 40% VALUBusy). launch_bounds (256,8):
// 64-VGPR cap (kernel measured 36 under (256,4)) -> 8-block/CU capacity.
// Cross-round ledger: every pass1 variant lands at ~50us with VALUBusy =
// busy/50 -> fixed latency bound; raising residency of the LOW-busy kernel
// is the remaining lever.
// Moments: M_k = sum B*q^k, M2_k = sum B^2*q^k (k=0..5, pos/neg);
// B = exp2(center*u), q = u*ln2, u = log2(1+|x|). Reconstruction per-feature
// in f64 in k_pick (5th-order Taylor, same truncation as r13 -> absmax 0.0).
// Slots: 0..5 Mp, 6..11 Mp2, 12..17 Mn, 18..23 Mn2, 24 u2p, 25 u2a,
// 26 npos, 27 flag (1 = direct sums from exact general path).
// Blocks >= CHv: parameter tensor reduction (overlapped, memory-bound).
// ---------------------------------------------------------------------------
__global__ __launch_bounds__(256, 8) void k_pass1(
    const float* __restrict__ x, const float* __restrict__ lam1,
    const float* __restrict__ lam2, const float* __restrict__ rp,
    const float* __restrict__ params, float* __restrict__ P1,
    double* __restrict__ pSums, int CHv, int rpt)
{
  const int c = blockIdx.x;
  const int t = threadIdx.x;

  if (c >= CHv) {
    // ---- parameter tensor partial reduction ----
    __shared__ double lred[2][4];
    const int b = c - CHv;
    const float4* p4 = (const float4*)params;
    double s = 0.0, q = 0.0;
    for (int i = b * 256 + t; i < PCOUNT / 4; i += PBLK * 256) {
      float4 v = p4[i];
      s += (double)v.x + (double)v.y + (double)v.z + (double)v.w;
      q += (double)v.x * v.x + (double)v.y * v.y
         + (double)v.z * v.z + (double)v.w * v.w;
    }
    s = wave_reduce_add(s); q = wave_reduce_add(q);
    const int w = t >> 6;
    if ((t & 63) == 0) { lred[0][w] = s; lred[1][w] = q; }
    __syncthreads();
    if (t == 0) {
      atomicAdd(&pSums[0], lred[0][0] + lred[0][1] + lred[0][2] + lred[0][3]);
      atomicAdd(&pSums[1], lred[1][0] + lred[1][1] + lred[1][2] + lred[1][3]);
    }
    return;
  }

  __shared__ int bad;
  if (t == 0) bad = 0;
  __syncthreads();

  const float L1 = lam1[t], L2 = lam2[t];
  const float An = 2.0f - L2;          // negative-branch center
  {
    bool b = (fabsf(L1) < F_EPS) || (fabsf(An) < F_EPS);
#pragma unroll
    for (int j = 1; j < 6; ++j) {
      float dp = 0.1f * rp[t * 10 + 2 * (j - 1)];
      float dn = -0.1f * rp[t * 10 + 2 * (j - 1) + 1];
      b = b || (fabsf(L1 + dp) < F_EPS) || (fabsf(An + dn) < F_EPS)
            || (fabsf(dp) > DELTA_MAX) || (fabsf(dn) > DELTA_MAX);
    }
    if (b) bad = 1;  // benign same-value race
  }
  __syncthreads();

  const float* xp = x + (size_t)c * rpt * NFEAT + t;
  float out[NSLOT];

  if (bad == 0) {
    // ---- moment path: plain loop, TLP hides latency ----
    float Mp[6], Mp2[6], Mn[6], Mn2[6];
#pragma unroll
    for (int k = 0; k < 6; ++k) { Mp[k] = 0.f; Mp2[k] = 0.f; Mn[k] = 0.f; Mn2[k] = 0.f; }
    float u2p = 0.f, u2a = 0.f, npos = 0.f;

#pragma unroll 4
    for (int i = 0; i < rpt; ++i) {
      const float v = xp[(size_t)i * NFEAT];
      const bool pos = v >= 0.0f;
      const float u = FAST_LOG2(1.0f + fabsf(v));
      u2a += u;
      u2p += pos ? u : 0.0f;
      npos += pos ? 1.0f : 0.0f;
      const float q = u * F_LN2;
      const float B = FAST_EXP2((pos ? L1 : An) * u);
      const float B2 = B * B;
      const float Bp = pos ? B : 0.0f;
      const float Bn = B - Bp;
      const float Cp = pos ? B2 : 0.0f;
      const float Cn = B2 - Cp;
      Mp[0] += Bp; Mp2[0] += Cp; Mn[0] += Bn; Mn2[0] += Cn;
      float qk = q;
      Mp[1] = fmaf(Bp, qk, Mp[1]); Mp2[1] = fmaf(Cp, qk, Mp2[1]);
      Mn[1] = fmaf(Bn, qk, Mn[1]); Mn2[1] = fmaf(Cn, qk, Mn2[1]);
#pragma unroll
      for (int k = 2; k < 6; ++k) {
        qk *= q;
        Mp[k] = fmaf(Bp, qk, Mp[k]); Mp2[k] = fmaf(Cp, qk, Mp2[k]);
        Mn[k] = fmaf(Bn, qk, Mn[k]); Mn2[k] = fmaf(Cn, qk, Mn2[k]);
      }
    }
#pragma unroll
    for (int k = 0; k < 6; ++k) {
      out[k]      = Mp[k];
      out[6 + k]  = Mp2[k];
      out[12 + k] = Mn[k];
      out[18 + k] = Mn2[k];
    }
    out[24] = u2p; out[25] = u2a; out[26] = npos; out[27] = 0.0f;
  } else {
    // ---- exact general path: direct sums (flag=1) ----
    float ga_p[6], ga_n[6], gs_p[6], gs_n[6], gt_p[6], gt_n[6];
#pragma unroll
    for (int j = 0; j < 6; ++j) {
      float dp = (j == 0) ? 0.0f : 0.1f * rp[t * 10 + 2 * (j - 1)];
      float dn = (j == 0) ? 0.0f : -0.1f * rp[t * 10 + 2 * (j - 1) + 1];
      float a1 = L1 + dp;
      float a2 = An + dn;
      bool z1 = fabsf(a1) < F_EPS;
      bool z2 = fabsf(a2) < F_EPS;
      ga_p[j] = z1 ? 0.0f : a1;
      gs_p[j] = z1 ? 0.0f : 1.0f / a1;
      gt_p[j] = z1 ? F_LN2 : 0.0f;
      ga_n[j] = z2 ? 0.0f : a2;
      gs_n[j] = z2 ? 0.0f : -1.0f / a2;
      gt_n[j] = z2 ? -F_LN2 : 0.0f;
    }
    float as[6], aq[6];
#pragma unroll
    for (int j = 0; j < 6; ++j) { as[j] = 0.f; aq[j] = 0.f; }
    float u2p = 0.f, u2a = 0.f;
    for (int i = 0; i < rpt; ++i) {
      float v = xp[(size_t)i * NFEAT];
      bool pos = v >= 0.0f;
      float u2 = FAST_LOG2(1.0f + fabsf(v));
      u2a += u2;
      u2p += pos ? u2 : 0.0f;
#pragma unroll
      for (int j = 0; j < 6; ++j) {
        float a  = pos ? ga_p[j] : ga_n[j];
        float s  = pos ? gs_p[j] : gs_n[j];
        float tt = pos ? gt_p[j] : gt_n[j];
        float e = FAST_EXP2(a * u2);
        float y = fmaf(tt, u2, fmaf(s, e, -s));
        as[j] += y;
        aq[j] = fmaf(y, y, aq[j]);
      }
    }
#pragma unroll
    for (int k = 0; k < NSLOT; ++k) out[k] = 0.0f;
#pragma unroll
    for (int j = 0; j < 6; ++j) { out[j] = as[j]; out[6 + j] = aq[j]; }
    out[24] = u2p; out[25] = u2a; out[26] = 0.0f; out[27] = 1.0f;
  }

#pragma unroll
  for (int k = 0; k < NSLOT; ++k)
    P1[((size_t)c * NSLOT + k) * NFEAT + t] = out[k];
}

// Stage A reduce: block (k, cg): S2[(k*RGRP+cg)*NFEAT+f] = sum over c-subrange.
__global__ __launch_bounds__(256) void k_reduce_S(
    const float* __restrict__ P1, double* __restrict__ S2, int CHv)
{
  const int k = blockIdx.x / RGRP;
  const int cg = blockIdx.x % RGRP;
  const int f = threadIdx.x;
  const int per = CHv / RGRP;
  const int c0 = cg * per;
  double a0 = 0.0, a1 = 0.0, a2 = 0.0, a3 = 0.0;
  for (int c = c0; c < c0 + per; c += 4) {
    a0 += (double)P1[((size_t)(c + 0) * NSLOT + k) * NFEAT + f];
    a1 += (double)P1[((size_t)(c + 1) * NSLOT + k) * NFEAT + f];
    a2 += (double)P1[((size_t)(c + 2) * NSLOT + k) * NFEAT + f];
    a3 += (double)P1[((size_t)(c + 3) * NSLOT + k) * NFEAT + f];
  }
  S2[((size_t)k * RGRP + cg) * NFEAT + f] = (a0 + a1) + (a2 + a3);
}

// One thread per feature: reconstruct 6 scores in f64, min, tie-average.
__global__ __launch_bounds__(256) void k_pick(
    const double* __restrict__ S2, const float* __restrict__ lam1,
    const float* __restrict__ lam2, const float* __restrict__ rp,
    float* __restrict__ bestL, int* __restrict__ tied,
    double* __restrict__ bitsF, int* __restrict__ anyTied)
{
  const int f = threadIdx.x;
  if (f == 0) *anyTied = 0;
  double s[NSLOT];
#pragma unroll
  for (int k = 0; k < NSLOT; ++k) {
    double a = 0.0;
#pragma unroll
    for (int cg = 0; cg < RGRP; ++cg)
      a += S2[((size_t)k * RGRP + cg) * NFEAT + f];
    s[k] = a;
  }
  const double n = (double)NROWS;
  const bool direct = s[27] > 0.5;
  const double npos = s[26];
  const double nneg = n - npos;
  const double sup = s[24];
  const double sun = s[25] - s[24];
  const float L1 = lam1[f], L2 = lam2[f];
  const double dAn = 2.0 - (double)L2;   // f64 negative-branch center
  double scores[6], al1[6], al2[6];
#pragma unroll
  for (int j = 0; j < 6; ++j) {
    float l1 = (j == 0) ? L1 : L1 + 0.1f * rp[f * 10 + 2 * (j - 1)];
    float l2 = (j == 0) ? L2 : L2 + 0.1f * rp[f * 10 + 2 * (j - 1) + 1];
    al1[j] = (double)l1; al2[j] = (double)l2;
    bool z1 = fabsf(l1) < F_EPS;
    bool z2 = fabsf(l2 - 2.0f) < F_EPS;
    double ccp = z1 ? -1.0 : (double)l1 - 1.0;
    double ccn = z2 ? -1.0 : 1.0 - (double)l2;
    double ljb = ccp * sup + ccn * sun;

    double sum_y, sum_y2;
    if (direct) {
      sum_y  = s[j];
      sum_y2 = s[6 + j];
    } else {
      const double dp  = (double)l1 - (double)L1;
      const double dnn = (2.0 - (double)l2) - dAn;
      const double sp = 1.0 / ((double)L1 + dp);
      const double sn = -1.0 / (dAn + dnn);
      const double Ep  = horner_exp(&s[0],  dp);
      const double Ep2 = horner_exp(&s[6],  2.0 * dp);
      const double En  = horner_exp(&s[12], dnn);
      const double En2 = horner_exp(&s[18], 2.0 * dnn);
      sum_y  = sp * (Ep - npos) + sn * (En - nneg);
      sum_y2 = sp * sp * (Ep2 - 2.0 * Ep + npos)
             + sn * sn * (En2 - 2.0 * En + nneg);
    }
    double mean = sum_y / n;
    double var = sum_y2 / n - mean * mean;
    var = var > 1e-12 ? var : 1e-12;
    scores[j] = n * (D_HALF_LOG2_2PIE + 0.5 * log2(var)) + ljb + D_LAMBDA_BITS;
  }
  double mn = scores[0];
#pragma unroll
  for (int j = 1; j < 6; ++j) mn = scores[j] < mn ? scores[j] : mn;
  double wsum = 0.0, b1 = 0.0, b2 = 0.0;
#pragma unroll
  for (int j = 0; j < 6; ++j) {
    double w = (scores[j] == mn) ? 1.0 : 0.0;
    wsum += w; b1 += w * al1[j]; b2 += w * al2[j];
  }
  bestL[2 * f]     = (float)(b1 / wsum);
  bestL[2 * f + 1] = (float)(b2 / wsum);
  const int isTied = (wsum > 1.5) ? 1 : 0;
  tied[f] = isTied;
  if (isTied) atomicOr(anyTied, 1);
  bitsF[f] = mn;   // unique min: identical to re-evaluating at best lambda
}

// Fallback pass 2 (only if some feature tied: averaged lambda is new).
__global__ __launch_bounds__(256) void k_pass2(
    const float* __restrict__ x, const float* __restrict__ bestL,
    const int* __restrict__ anyTied, float* __restrict__ P2)
{
  if (*anyTied == 0) return;
  const int t = threadIdx.x;
  const int c = blockIdx.x;
  const int rpt = NROWS / CH2;   // 128
  const float l1 = bestL[2 * t], l2 = bestL[2 * t + 1];
  const bool z1 = fabsf(l1) < F_EPS;
  const bool z2 = fabsf(l2 - 2.0f) < F_EPS;
  const float tm = 2.0f - l2;
  const float a_p = z1 ? 0.f : l1,  s_pv = z1 ? 0.f : 1.f / l1,  t_pv = z1 ? F_LN2 : 0.f;
  const float a_n = z2 ? 0.f : tm,  s_nv = z2 ? 0.f : -1.f / tm, t_nv = z2 ? -F_LN2 : 0.f;

  float sy = 0.f, sq = 0.f;
  const float* xp = x + (size_t)c * rpt * NFEAT + t;
  for (int i = 0; i < rpt; ++i) {
    float v = xp[(size_t)i * NFEAT];
    bool pos = v >= 0.0f;
    float u2 = FAST_LOG2(1.0f + fabsf(v));
    float a  = pos ? a_p : a_n;
    float s  = pos ? s_pv : s_nv;
    float tt = pos ? t_pv : t_nv;
    float e = FAST_EXP2(a * u2);
    float y = fmaf(tt, u2, fmaf(s, e, -s));
    sy += y;
    sq = fmaf(y, y, sq);
  }
  P2[((size_t)c * 2 + 0) * NFEAT + t] = sy;
  P2[((size_t)c * 2 + 1) * NFEAT + t] = sq;
}

__global__ __launch_bounds__(64) void k_featbits(
    const float* __restrict__ P1, const float* __restrict__ P2,
    const float* __restrict__ bestL, const int* __restrict__ tied,
    double* __restrict__ bitsF, int CHv)
{
  const int f = blockIdx.x;
  if (!tied[f]) return;
  const int lane = threadIdx.x;
  double s0 = 0.0, s1 = 0.0, sup = 0.0, sua = 0.0;
  for (int c = lane; c < CH2; c += 64) {
    s0 += (double)P2[((size_t)c * 2 + 0) * NFEAT + f];
    s1 += (double)P2[((size_t)c * 2 + 1) * NFEAT + f];
  }
  for (int c = lane; c < CHv; c += 64) {
    sup += (double)P1[((size_t)c * NSLOT + 24) * NFEAT + f];
    sua += (double)P1[((size_t)c * NSLOT + 25) * NFEAT + f];
  }
  s0 = wave_reduce_add(s0); s1 = wave_reduce_add(s1);
  sup = wave_reduce_add(sup); sua = wave_reduce_add(sua);
  if (lane == 0) {
    const float l1 = bestL[2 * f], l2 = bestL[2 * f + 1];
    bool z1 = fabsf(l1) < F_EPS;
    bool z2 = fabsf(l2 - 2.0f) < F_EPS;
    double ccp = z1 ? -1.0 : (double)l1 - 1.0;
    double ccn = z2 ? -1.0 : 1.0 - (double)l2;
    double ljb = ccp * sup + ccn * (sua - sup);
    const double n = (double)NROWS;
    double mean = s0 / n;
    double var = s1 / n - mean * mean;
    var = var > 1e-12 ? var : 1e-12;
    bitsF[f] = n * (D_HALF_LOG2_2PIE + 0.5 * log2(var)) + ljb + D_LAMBDA_BITS;
  }
}

__global__ __launch_bounds__(256) void k_final(
    const double* __restrict__ bitsF, const double* __restrict__ pSums,
    float* __restrict__ out)
{
  __shared__ double l[4];
  double s = bitsF[threadIdx.x];
  s = wave_reduce_add(s);
  int w = threadIdx.x >> 6;
  if ((threadIdx.x & 63) == 0) l[w] = s;
  __syncthreads();
  if (threadIdx.x == 0) {
    double data = l[0] + l[1] + l[2] + l[3];
    const double n = (double)PCOUNT;
    double mean = pSums[0] / n;
    double var = pSums[1] / n - mean * mean;
    var = var > 1e-12 ? var : 1e-12;
    double model = n * (D_HALF_LOG2_2PIE + 0.5 * log2(var)) + D_LAMBDA_BITS;
    out[0] = (float)(data + model);
  }
}

extern "C" void kernel_launch(void* const* d_in, const int* in_sizes, int n_in,
                              void* d_out, int out_size, void* d_ws, size_t ws_size,
                              hipStream_t stream)
{
  const float* x      = (const float*)d_in[0];
  const float* lam1   = (const float*)d_in[1];
  const float* lam2   = (const float*)d_in[2];
  const float* rp     = (const float*)d_in[3];
  const float* params = (const float*)d_in[4];

  char* ws = (char*)d_ws;
  double* pSums  = (double*)ws;                 // 16 B   -> 16
  float*  bestL  = (float*)(ws + 16);           // 2048   -> 2064
  double* bitsF  = (double*)(ws + 2064);        // 2048   -> 4112
  int*    tied   = (int*)(ws + 4112);           // 1024   -> 5136
  int*    anyT   = (int*)(ws + 5136);           // 4      -> pad 5152
  double* S2     = (double*)(ws + 5152);        // 28*16*256*8 = 917504 -> 922656
  float*  P1     = (float*)(ws + 922656);

  // chunk count: CHv=1024, fall back if ws small
  int CHv = 1024;
  while (CHv > 128) {
    size_t need = 922656 + (size_t)CHv * NSLOT * NFEAT * 4
                         + (size_t)CH2 * 2 * NFEAT * 4;
    if (need <= ws_size) break;
    CHv >>= 1;
  }
  float* P2 = (float*)(ws + 922656 + (size_t)CHv * NSLOT * NFEAT * 4);
  int rpt = NROWS / CHv;   // 64 at CHv=1024

  (void)hipMemsetAsync(pSums, 0, 16, stream);
  k_pass1<<<CHv + PBLK, 256, 0, stream>>>(x, lam1, lam2, rp, params, P1,
                                          pSums, CHv, rpt);
  k_reduce_S<<<NSLOT * RGRP, 256, 0, stream>>>(P1, S2, CHv);
  k_pick<<<1, 256, 0, stream>>>(S2, lam1, lam2, rp, bestL, tied, bitsF, anyT);
  k_pass2<<<CH2, 256, 0, stream>>>(x, bestL, anyT, P2);
  k_featbits<<<NFEAT, 64, 0, stream>>>(P1, P2, bestL, tied, bitsF, CHv);
  k_final<<<1, 256, 0, stream>>>(bitsF, pSums, (float*)d_out);
}